// Round 6
// baseline (272.018 us; speedup 1.0000x reference)
//
#include <hip/hip_runtime.h>
#include <math.h>

#define N_MELS   128
#define N_FFT    2048
#define HOP      512
#define BATCH    8
#define S_LEN    661500
#define CH       2
#define T_FRAMES 1292            // 1 + S_LEN/HOP
#define NBINS    1025            // 1 + N_FFT/2

#define ANG 0.003067961575771282f   // 2*pi/2048

// d_ws layout (byte offsets)
#define WS_WIN     0        // float[2048]   hann window
#define WS_TW      8192     // float2[2048]  W_2048^j
#define WS_WBEG    24576    // int[128]      4-aligned start bin per mel
#define WS_WN4     25088    // int[128]      float4 iteration count per mel
#define WS_WTAB    25600    // float[128*64] dense zero-padded mel weights

// pw planes: [hh*PW_FR + c*PW_OFF + f], hh in 0..3 (4 frames), c in 0..1.
// PW_FR ≡ 8, PW_OFF ≡ 4 (mod 32 banks): the 4 hh-planes start at bank
// 0/8/16/24, channel 1 at +4. Max idx 3*2120+1060+1059 = 8479 < 9216.
#define PW_OFF   1060       // channel-plane stride (floats)
#define PW_FR    2120       // frame-plane stride (floats)

// Padded exchange buffer: element e in [0,2048) lives at Z[e + 2*(e>>4)].
// 2304 float2 = 1152 float4 = 18432 B per buffer; TWO buffers = 36864 B.
// R2 lesson: 36.9KB at 256-thread blocks collapses occupancy (16 waves/CU).
// Fix: 512-thread blocks -> 4 blocks/CU x 8 waves = 32 waves/CU preserved,
// and each barrier now serves TWO frames (halves) at once.
#define ZF4 1152            // float4 per buffer

typedef float vf2 __attribute__((ext_vector_type(2)));

__device__ __forceinline__ vf2 cnegi(vf2 z){ return (vf2){ z.y, -z.x }; } // -i*z
__device__ __forceinline__ vf2 cmul(vf2 a, vf2 b){
    vf2 t = a.yy * b.yx;                 // v_pk_mul
    vf2 s = (vf2){ -t.x, t.y };
    return a.xx * b + s;                 // v_pk_fma
}

// radix-8 DIF butterfly: b[k] = sum_j a[j] * W8^{jk}, W8 = exp(-i*pi/4)
__device__ __forceinline__ void bfly8(const vf2* a, vf2* b) {
    const float C = 0.70710678118654752f;
    vf2 e0=a[0]+a[4], e1=a[1]+a[5], e2=a[2]+a[6], e3=a[3]+a[7];
    vf2 o0=a[0]-a[4], o1=a[1]-a[5], o2=a[2]-a[6], o3=a[3]-a[7];
    vf2 t1 = (o1 + cnegi(o1)) * C;       // o1*W8^1
    vf2 t2 = cnegi(o2);                  // o2*W8^2
    vf2 t3 = (cnegi(o3) - o3) * C;       // o3*W8^3
    {
        vf2 s0=e0+e2, d0=e0-e2;
        vf2 s1=e1+e3, d1=e1-e3;
        b[0]=s0+s1; b[4]=s0-s1;
        vf2 nd1=cnegi(d1);
        b[2]=d0+nd1; b[6]=d0-nd1;
    }
    {
        vf2 s0=o0+t2, d0=o0-t2;
        vf2 s1=t1+t3, d1=t1-t3;
        b[1]=s0+s1; b[5]=s0-s1;
        vf2 nd1=cnegi(d1);
        b[3]=d0+nd1; b[7]=d0-nd1;
    }
}

// One stage for one frame: twiddles from TABLE (w1^k = tw[k*tb], k*tb<2048
// always since tb<=255, k<=7). 7 VMEM loads replace the serial cmul tree:
// loads issue before bfly8 and hide under it; VALU (the hot pipe) shrinks.
__device__ __forceinline__ void stage_tw(vf2* r, const vf2* tw, int tb) {
    vf2 tws[7];
    #pragma unroll
    for (int j = 0; j < 7; ++j) tws[j] = tw[(j+1)*tb];
    vf2 bq[8];
    bfly8(r, bq);
    r[0] = bq[0];
    #pragma unroll
    for (int j = 0; j < 7; ++j) r[j+1] = cmul(tws[j], bq[j+1]);
}

// stage-4 radix-4 (s=512, twiddle-free) butterfly
__device__ __forceinline__ void bf4(const vf2* I, vf2* O) {
    vf2 apc=I[0]+I[2], amc=I[0]-I[2];
    vf2 bpd=I[1]+I[3], bmd=I[1]-I[3];
    vf2 nb = cnegi(bmd);
    O[0]=apc+bpd; O[1]=amc+nb;
    O[2]=apc-bpd; O[3]=amc-nb;
}

// two-channel untangle: (|A|^2, |B|^2) for Zf, Zm = Z[N-f]
__device__ __forceinline__ vf2 upair(vf2 Zf, vf2 Zm) {
    vf2 B = (vf2){ Zm.x, -Zm.y };        // conj
    vf2 e = Zf + B;
    vf2 d = Zf - B;
    vf2 ee = e * e;
    vf2 dd = d * d;
    return (vf2){ 0.25f*(ee.x + ee.y), 0.25f*(dd.x + dd.y) };
}

__device__ __forceinline__ void store_frame(float* pwf, int lt, const vf2* p)
{
    if (lt == 0) {
        pwf[0]    = p[0].x; pwf[PW_OFF+0]    = p[0].y;
        pwf[512]  = p[1].x; pwf[PW_OFF+512]  = p[1].y;
        pwf[1024] = p[2].x; pwf[PW_OFF+1024] = p[2].y;
        pwf[256]  = p[3].x; pwf[PW_OFF+256]  = p[3].y;
        pwf[768]  = p[4].x; pwf[PW_OFF+768]  = p[4].y;
    } else {
        pwf[lt]      = p[0].x; pwf[PW_OFF+lt]      = p[0].y;
        pwf[lt+512]  = p[1].x; pwf[PW_OFF+lt+512]  = p[1].y;
        pwf[512-lt]  = p[2].x; pwf[PW_OFF+512-lt]  = p[2].y;
        pwf[1024-lt] = p[3].x; pwf[PW_OFF+1024-lt] = p[3].y;
    }
}

// --- setup: blocks 0..31: mel rows (4 per block, 1 per wave);
//            blocks 32..39: window + twiddle tables ---
__global__ __launch_bounds__(256) void setup_kernel(
        const float* __restrict__ fb, float* __restrict__ ws) {
    int blk = blockIdx.x;
    if (blk >= 32) {
        int i = (blk - 32) * 256 + threadIdx.x;
        float*  win = ws;
        float2* tw  = (float2*)((char*)ws + WS_TW);
        win[i] = 0.5f - 0.5f * cosf(ANG * (float)i);
        float sn, cs; sincosf(-ANG * (float)i, &sn, &cs);
        tw[i] = make_float2(cs, sn);
    } else {
        int m    = blk * 4 + (threadIdx.x >> 6);   // one mel row per wave
        int lane = threadIdx.x & 63;
        int*   wbeg = (int*)((char*)ws + WS_WBEG);
        int*   wn4  = (int*)((char*)ws + WS_WN4);
        float* wtab = (float*)((char*)ws + WS_WTAB);
        const float* row = fb + m * NBINS;
        int s = NBINS;      // first nonzero bin
        int e = 0;          // last nonzero bin
        for (int f = lane; f < NBINS; f += 64) {
            if (row[f] != 0.0f) { if (f < s) s = f; if (f > e) e = f; }
        }
        #pragma unroll
        for (int o = 32; o; o >>= 1) {
            s = min(s, __shfl_xor(s, o));
            e = max(e, __shfl_xor(e, o));
        }
        int a0 = s & ~3;              // 4-aligned start; slaney span<=54+3<64
        if (a0 > NBINS - 1) a0 = (NBINS - 1) & ~3;
        int n4 = (e - a0 + 4) >> 2;   // ceil((e-a0+1)/4)
        if (n4 < 1) n4 = 1;
        if (n4 > 16) n4 = 16;
        if (lane == 0) { wbeg[m] = a0; wn4[m] = n4; }
        int f = a0 + lane;
        wtab[(m << 6) + lane] = (f < NBINS) ? row[f] : 0.0f;
    }
}

// --- main: 512 threads, 4 frames/block. Half-block fh (threads fh*256..)
// pipes frame t0+2p+fh through buffer fh; barriers serve both halves, so
// barriers/frame halve (13 per 4 frames vs 13 per 2 before) while waves/CU
// stay at 32 (4 blocks x 36864 B = 147 KB LDS).
__global__ __launch_bounds__(512, 8) void mel_spec_kernel(
        const float* __restrict__ x, const float* __restrict__ fb,
        const float* __restrict__ ws, float* __restrict__ out) {
    __shared__ float4 Zq[2*ZF4];         // 36864 B: buf0 | buf1 (pw spans both)
    float* pwb = (float*)Zq;             // pw planes: [hh*2120 + c*1060 + f]

    const float* win  = ws;
    const vf2*   tw   = (const vf2*)((const char*)ws + WS_TW);
    const int*   wbeg = (const int*)((const char*)ws + WS_WBEG);
    const int*   wn4  = (const int*)((const char*)ws + WS_WN4);
    const float* wtab = (const float*)((const char*)ws + WS_WTAB);

    const int tid = threadIdx.x;
    const int lt  = tid & 255;            // lane within half-block
    const int fh  = tid >> 8;             // half-block = frame-of-pair
    const int bid = blockIdx.x;
    const int b   = bid & 7;              // XCD-contiguous: one batch item/XCD
    const int t0  = (bid >> 3) * 4;       // frames t0 .. t0+3

    float4* Zqh = Zq + fh * ZF4;          // this half's exchange buffer
    vf2*    Z2h = (vf2*)Zqh;

    const vf2* xb = (const vf2*)x + (size_t)b * S_LEN;

    const int rb    = lt + 2*(lt>>4);     // OFFE(lt); +288 per 256 elements
    const int b2    = (lt == 0) ? 256 : 512 - lt;
    const int rb2   = b2 + 2*(b2>>4);
    const int f4    = 4*lt + (lt>>1);     // float4 index of OFFE(8*lt)/2
    const int base2 = (lt & 7) + 72*(lt >> 3);
    const int q3    = lt & 63;
    const int base3 = q3 + 2*(q3>>4) + 576*(lt >> 6);
    const int tb1   = lt;
    const int tb2   = lt & ~7;
    const int tb3   = lt & ~63;

    float wv[8];
    #pragma unroll
    for (int k = 0; k < 8; ++k) wv[k] = win[lt + 256*k];

    // Full 2048-pt FFT + untangle for ONE frame through this half's buffer.
    // 6 barriers, all block-wide (both halves run in lockstep; the input
    // fast/slow branch is wave-uniform and contains no barriers).
    auto do_frame = [&](int fr, vf2* pout) {
        const int tb = fr*HOP - (N_FFT/2);
        vf2 r[8];
        if (tb >= 0 && tb + (N_FFT - 1) < S_LEN) {
            #pragma unroll
            for (int k = 0; k < 8; ++k) r[k] = xb[tb + lt + 256*k] * wv[k];
        } else {
            #pragma unroll
            for (int k = 0; k < 8; ++k) {
                int s = tb + lt + 256*k;
                if (s < 0) s = -s; else if (s >= S_LEN) s = 2*S_LEN - 2 - s;
                r[k] = xb[s] * wv[k];
            }
        }
        // Stage 1: radix-8, s=1. Outputs e = 8*lt + k (b128 writes).
        stage_tw(r, tw, tb1);
        #pragma unroll
        for (int j = 0; j < 4; ++j)
            Zqh[f4+j] = make_float4(r[2*j].x, r[2*j].y, r[2*j+1].x, r[2*j+1].y);
        __syncthreads();
        #pragma unroll
        for (int k = 0; k < 8; ++k) r[k] = Z2h[rb + 288*k];
        __syncthreads();
        // Stage 2: radix-8, s=8. Outputs e = q + 64a + 8k.
        stage_tw(r, tw, tb2);
        #pragma unroll
        for (int k = 0; k < 8; ++k) Z2h[base2 + 8*k + 2*(k>>1)] = r[k];
        __syncthreads();
        #pragma unroll
        for (int k = 0; k < 8; ++k) r[k] = Z2h[rb + 288*k];
        __syncthreads();
        // Stage 3: radix-8, s=64. Outputs e = q + 512a + 64k.
        stage_tw(r, tw, tb3);
        #pragma unroll
        for (int k = 0; k < 8; ++k) Z2h[base3 + 72*k] = r[k];
        __syncthreads();
        vf2 F1[4], F2[4];
        #pragma unroll
        for (int k = 0; k < 4; ++k) { F1[k] = Z2h[rb + 576*k]; F2[k] = Z2h[rb2 + 576*k]; }
        __syncthreads();                  // buffer free for next use
        // Stage 4 + untangle -> registers (static indices only)
        vf2 O1[4], O2[4];
        bf4(F1, O1); bf4(F2, O2);
        if (lt == 0) {
            pout[0] = upair(O1[0], O1[0]);
            pout[1] = upair(O1[1], O1[3]);
            pout[2] = upair(O1[2], O1[2]);
            pout[3] = upair(O2[0], O2[3]);
            pout[4] = upair(O2[1], O2[2]);
        } else {
            pout[0] = upair(O1[0], O2[3]);
            pout[1] = upair(O1[1], O2[2]);
            pout[2] = upair(O2[0], O1[3]);
            pout[3] = upair(O2[1], O1[2]);
            pout[4] = (vf2){0.0f, 0.0f};
        }
    };

    vf2 p0[5], p1[5];
    do_frame(t0 + fh,     p0);            // pair 0: frames t0, t0+1
    do_frame(t0 + 2 + fh, p1);            // pair 1: frames t0+2, t0+3

    // pw planes for all 4 frames (p0/p1 deferred in regs until buffers free).
    store_frame(pwb + fh*PW_FR,     lt, p0);      // plane hh = fh
    store_frame(pwb + (2+fh)*PW_FR, lt, p1);      // plane hh = 2+fh
    // Zero the 35-float gap [1025,1060) after each of the 8 planes.
    if (tid < 280) {
        int pl = tid / 35, o = tid - pl*35;
        pwb[(pl>>1)*PW_FR + (pl&1)*PW_OFF + 1025 + o] = 0.0f;
    }
    __syncthreads();

    // Mel projection: one thread per (m, frame h) -- 128x4 = 512 exact.
    // Variable-length loop (wn4[m] = 2..15 float4 iters); packed-FMA dot.
    {
        int m  = tid >> 2;
        int h  = tid & 3;                      // frame t0+h
        int a0 = wbeg[m];
        int n4 = wn4[m];
        const float4* wt4 = (const float4*)(wtab + (m << 6));
        const float4* q0  = (const float4*)(pwb + h*PW_FR + a0);           // ch0
        const float4* q1  = (const float4*)(pwb + h*PW_FR + PW_OFF + a0);  // ch1
        vf2 acc0 = (vf2){0.0f, 0.0f};
        vf2 acc1 = (vf2){0.0f, 0.0f};
        for (int j = 0; j < n4; ++j) {
            float4 w4 = wt4[j];
            float4 r0 = q0[j];
            float4 r1 = q1[j];
            vf2 wlo = (vf2){w4.x, w4.y}, whi = (vf2){w4.z, w4.w};
            acc0 += wlo * (vf2){r0.x, r0.y};
            acc0 += whi * (vf2){r0.z, r0.w};
            acc1 += wlo * (vf2){r1.x, r1.y};
            acc1 += whi * (vf2){r1.z, r1.w};
        }
        size_t base = (((size_t)b * N_MELS + m) * T_FRAMES + t0 + h) * CH;
        *(float2*)(out + base) = make_float2(acc0.x + acc0.y, acc1.x + acc1.y);
    }
}

extern "C" void kernel_launch(void* const* d_in, const int* in_sizes, int n_in,
                              void* d_out, int out_size, void* d_ws, size_t ws_size,
                              hipStream_t stream) {
    const float* x  = (const float*)d_in[0];
    const float* fb = (const float*)d_in[1];
    float* out = (float*)d_out;
    float* ws  = (float*)d_ws;

    setup_kernel<<<40, 256, 0, stream>>>(fb, ws);
    mel_spec_kernel<<<BATCH * (T_FRAMES/4), 512, 0, stream>>>(x, fb, ws, out);
}

// Round 7
// 137.411 us; speedup vs baseline: 1.9796x; 1.9796x over previous
//
#include <hip/hip_runtime.h>
#include <math.h>

#define N_MELS   128
#define N_FFT    2048
#define HOP      512
#define BATCH    8
#define S_LEN    661500
#define CH       2
#define T_FRAMES 1292            // 1 + S_LEN/HOP
#define NBINS    1025            // 1 + N_FFT/2

#define ANG 0.003067961575771282f   // 2*pi/2048

// d_ws layout (byte offsets)
#define WS_WIN     0        // float[2048]   hann window
#define WS_TW      8192     // float2[2048]  W_2048^j
#define WS_WBEG    24576    // int[128]      4-aligned start bin per mel
#define WS_WN4     25088    // int[128]      float4 iteration count per mel
#define WS_WTAB    25600    // float[128*64] dense zero-padded mel weights

// pw planes: [h*PW_FR + c*PW_OFF + f], h in 0..1, c in 0..1.
// Plane starts mod 32 banks: 0 / 4 / 8 / 12 -> the mel (h,c) thread quad
// reads disjoint 4-bank groups. Max idx 2120+1060+1059 = 4239 < 4608 (buf0).
#define PW_OFF   1060       // channel-plane stride (floats)
#define PW_FR    2120       // frame-plane stride (floats)

// Padded exchange buffer: element e in [0,2048) lives at Z[e + 2*(e>>4)].
// 1152 float4 = 18432 B per buffer; two buffers = 36864 B.
// R2 lesson: occupancy must stay 32 waves/CU -> 512-thr blocks, 4 blocks/CU.
// R6 lesson: deferred multi-frame state spills under the 64-VGPR cap ->
// each thread owns exactly ONE frame (16 VGPRs of FFT state, no deferral).
#define ZF4 1152            // float4 per buffer

typedef float vf2 __attribute__((ext_vector_type(2)));

__device__ __forceinline__ vf2 cnegi(vf2 z){ return (vf2){ z.y, -z.x }; } // -i*z
__device__ __forceinline__ vf2 cmul(vf2 a, vf2 b){
    vf2 t = a.yy * b.yx;                 // v_pk_mul
    vf2 s = (vf2){ -t.x, t.y };
    return a.xx * b + s;                 // v_pk_fma
}

// radix-8 DIF butterfly: b[k] = sum_j a[j] * W8^{jk}, W8 = exp(-i*pi/4)
__device__ __forceinline__ void bfly8(const vf2* a, vf2* b) {
    const float C = 0.70710678118654752f;
    vf2 e0=a[0]+a[4], e1=a[1]+a[5], e2=a[2]+a[6], e3=a[3]+a[7];
    vf2 o0=a[0]-a[4], o1=a[1]-a[5], o2=a[2]-a[6], o3=a[3]-a[7];
    vf2 t1 = (o1 + cnegi(o1)) * C;       // o1*W8^1
    vf2 t2 = cnegi(o2);                  // o2*W8^2
    vf2 t3 = (cnegi(o3) - o3) * C;       // o3*W8^3
    {
        vf2 s0=e0+e2, d0=e0-e2;
        vf2 s1=e1+e3, d1=e1-e3;
        b[0]=s0+s1; b[4]=s0-s1;
        vf2 nd1=cnegi(d1);
        b[2]=d0+nd1; b[6]=d0-nd1;
    }
    {
        vf2 s0=o0+t2, d0=o0-t2;
        vf2 s1=t1+t3, d1=t1-t3;
        b[1]=s0+s1; b[5]=s0-s1;
        vf2 nd1=cnegi(d1);
        b[3]=d0+nd1; b[7]=d0-nd1;
    }
}

// One stage: twiddles from TABLE (w1^k = tw[k*tb], k*tb <= 7*255 < 2048).
// 7 VMEM gathers (L1-hot, idle pipe) replace the serial cmul tree (hot VALU).
__device__ __forceinline__ void stage_tw(vf2* r, const vf2* tw, int tb) {
    vf2 tws[7];
    #pragma unroll
    for (int j = 0; j < 7; ++j) tws[j] = tw[(j+1)*tb];
    vf2 bq[8];
    bfly8(r, bq);
    r[0] = bq[0];
    #pragma unroll
    for (int j = 0; j < 7; ++j) r[j+1] = cmul(tws[j], bq[j+1]);
}

// stage-4 radix-4 (s=512, twiddle-free) butterfly
__device__ __forceinline__ void bf4(const vf2* I, vf2* O) {
    vf2 apc=I[0]+I[2], amc=I[0]-I[2];
    vf2 bpd=I[1]+I[3], bmd=I[1]-I[3];
    vf2 nb = cnegi(bmd);
    O[0]=apc+bpd; O[1]=amc+nb;
    O[2]=apc-bpd; O[3]=amc-nb;
}

// two-channel untangle: (|A|^2, |B|^2) for Zf, Zm = Z[N-f]
__device__ __forceinline__ vf2 upair(vf2 Zf, vf2 Zm) {
    vf2 B = (vf2){ Zm.x, -Zm.y };        // conj
    vf2 e = Zf + B;
    vf2 d = Zf - B;
    vf2 ee = e * e;
    vf2 dd = d * d;
    return (vf2){ 0.25f*(ee.x + ee.y), 0.25f*(dd.x + dd.y) };
}

// --- setup: blocks 0..31: mel rows (4 per block, 1 per wave);
//            blocks 32..39: window + twiddle tables ---
__global__ __launch_bounds__(256) void setup_kernel(
        const float* __restrict__ fb, float* __restrict__ ws) {
    int blk = blockIdx.x;
    if (blk >= 32) {
        int i = (blk - 32) * 256 + threadIdx.x;
        float*  win = ws;
        float2* tw  = (float2*)((char*)ws + WS_TW);
        win[i] = 0.5f - 0.5f * cosf(ANG * (float)i);
        float sn, cs; sincosf(-ANG * (float)i, &sn, &cs);
        tw[i] = make_float2(cs, sn);
    } else {
        int m    = blk * 4 + (threadIdx.x >> 6);   // one mel row per wave
        int lane = threadIdx.x & 63;
        int*   wbeg = (int*)((char*)ws + WS_WBEG);
        int*   wn4  = (int*)((char*)ws + WS_WN4);
        float* wtab = (float*)((char*)ws + WS_WTAB);
        const float* row = fb + m * NBINS;
        int s = NBINS;      // first nonzero bin
        int e = 0;          // last nonzero bin
        for (int f = lane; f < NBINS; f += 64) {
            if (row[f] != 0.0f) { if (f < s) s = f; if (f > e) e = f; }
        }
        #pragma unroll
        for (int o = 32; o; o >>= 1) {
            s = min(s, __shfl_xor(s, o));
            e = max(e, __shfl_xor(e, o));
        }
        int a0 = s & ~3;              // 4-aligned start; slaney span<=54+3<64
        if (a0 > NBINS - 1) a0 = (NBINS - 1) & ~3;
        int n4 = (e - a0 + 4) >> 2;   // ceil((e-a0+1)/4)
        if (n4 < 1) n4 = 1;
        if (n4 > 16) n4 = 16;
        if (lane == 0) { wbeg[m] = a0; wn4[m] = n4; }
        int f = a0 + lane;
        wtab[(m << 6) + lane] = (f < NBINS) ? row[f] : 0.0f;
    }
}

// --- main: 512 threads, 2 frames/block, ONE frame per half-block.
// Half fh (threads fh*256..fh*256+255) pipes frame t0+fh through buffer fh;
// every barrier serves both frames -> 7 barriers per 2 frames (R4: 13).
// Per-thread FFT state = one frame (r[8] = 16 VGPRs) -> no spill under the
// (512,8) 64-VGPR cap. 4 blocks x 36864 B = 147 KB LDS, 32 waves/CU.
__global__ __launch_bounds__(512, 8) void mel_spec_kernel(
        const float* __restrict__ x, const float* __restrict__ fb,
        const float* __restrict__ ws, float* __restrict__ out) {
    __shared__ float4 Zq[2*ZF4];         // 36864 B: buf0 | buf1
    float* pwb = (float*)Zq;             // pw planes: [h*2120 + c*1060 + f]

    const float* win  = ws;
    const vf2*   tw   = (const vf2*)((const char*)ws + WS_TW);
    const int*   wbeg = (const int*)((const char*)ws + WS_WBEG);
    const int*   wn4  = (const int*)((const char*)ws + WS_WN4);
    const float* wtab = (const float*)((const char*)ws + WS_WTAB);

    const int tid = threadIdx.x;
    const int lt  = tid & 255;            // lane within half-block
    const int fh  = tid >> 8;             // half-block = frame index
    const int bid = blockIdx.x;
    const int b   = bid & 7;              // XCD-contiguous: one batch item/XCD
    const int t0  = (bid >> 3) * 2;       // frames t0, t0+1

    float4* Zqh = Zq + fh * ZF4;          // this half's exchange buffer
    vf2*    Z2h = (vf2*)Zqh;

    const vf2* xb = (const vf2*)x + (size_t)b * S_LEN;
    const int tb  = (t0 + fh)*HOP - (N_FFT/2);   // this half's frame start

    const int rb    = lt + 2*(lt>>4);     // OFFE(lt); +288 per 256 elements
    const int b2    = (lt == 0) ? 256 : 512 - lt;
    const int rb2   = b2 + 2*(b2>>4);
    const int f4    = 4*lt + (lt>>1);     // float4 index of OFFE(8*lt)/2
    const int base2 = (lt & 7) + 72*(lt >> 3);
    const int q3    = lt & 63;
    const int base3 = q3 + 2*(q3>>4) + 576*(lt >> 6);

    // ---- Input + window (branch is half-uniform; waves don't straddle
    // halves; no barrier inside).
    vf2 r[8];
    if (tb >= 0 && tb + (N_FFT - 1) < S_LEN) {
        #pragma unroll
        for (int k = 0; k < 8; ++k)
            r[k] = xb[tb + lt + 256*k] * win[lt + 256*k];
    } else {
        #pragma unroll
        for (int k = 0; k < 8; ++k) {
            int s = tb + lt + 256*k;
            if (s < 0) s = -s; else if (s >= S_LEN) s = 2*S_LEN - 2 - s;
            r[k] = xb[s] * win[lt + 256*k];
        }
    }

    // ======== Stage 1: radix-8, s=1. Outputs e = 8*lt + k (b128 writes).
    stage_tw(r, tw, lt);
    #pragma unroll
    for (int j = 0; j < 4; ++j)
        Zqh[f4+j] = make_float4(r[2*j].x, r[2*j].y, r[2*j+1].x, r[2*j+1].y);
    __syncthreads();
    #pragma unroll
    for (int k = 0; k < 8; ++k) r[k] = Z2h[rb + 288*k];
    __syncthreads();

    // ======== Stage 2: radix-8, s=8. Outputs e = q + 64a + 8k.
    stage_tw(r, tw, lt & ~7);
    #pragma unroll
    for (int k = 0; k < 8; ++k) Z2h[base2 + 8*k + 2*(k>>1)] = r[k];
    __syncthreads();
    #pragma unroll
    for (int k = 0; k < 8; ++k) r[k] = Z2h[rb + 288*k];
    __syncthreads();

    // ======== Stage 3: radix-8, s=64. Outputs e = q + 512a + 64k.
    stage_tw(r, tw, lt & ~63);
    #pragma unroll
    for (int k = 0; k < 8; ++k) Z2h[base3 + 72*k] = r[k];
    __syncthreads();
    // Stage-4 butterfly pair: b1 = lt, b2 = 512-lt (lt=0 -> {0,256}).
    vf2 F1[4], F2[4];
    #pragma unroll
    for (int k = 0; k < 4; ++k) { F1[k] = Z2h[rb + 576*k]; F2[k] = Z2h[rb2 + 576*k]; }
    __syncthreads();                      // buffers free; pw stores may alias

    // ======== Stage 4 + untangle (registers), then pw planes.
    // All pw planes (4240 floats) live in buf0; fenced by the sync above.
    {
        vf2 O1[4], O2[4];
        bf4(F1, O1); bf4(F2, O2);
        float* pwf = pwb + fh*PW_FR;      // this half's frame plane (h = fh)
        if (lt == 0) {
            vf2 p;
            p = upair(O1[0], O1[0]); pwf[0]    = p.x; pwf[PW_OFF+0]    = p.y;
            p = upair(O1[1], O1[3]); pwf[512]  = p.x; pwf[PW_OFF+512]  = p.y;
            p = upair(O1[2], O1[2]); pwf[1024] = p.x; pwf[PW_OFF+1024] = p.y;
            p = upair(O2[0], O2[3]); pwf[256]  = p.x; pwf[PW_OFF+256]  = p.y;
            p = upair(O2[1], O2[2]); pwf[768]  = p.x; pwf[PW_OFF+768]  = p.y;
        } else {
            vf2 p;
            p = upair(O1[0], O2[3]); pwf[lt]      = p.x; pwf[PW_OFF+lt]      = p.y;
            p = upair(O1[1], O2[2]); pwf[lt+512]  = p.x; pwf[PW_OFF+lt+512]  = p.y;
            p = upair(O2[0], O1[3]); pwf[512-lt]  = p.x; pwf[PW_OFF+512-lt]  = p.y;
            p = upair(O2[1], O1[2]); pwf[1024-lt] = p.x; pwf[PW_OFF+1024-lt] = p.y;
        }
    }
    // Zero the 35-float gap [1025,1060) after each of the 4 planes.
    if (tid < 140) {
        int pl = tid / 35, o = tid - pl*35;
        pwb[(pl>>1)*PW_FR + (pl&1)*PW_OFF + 1025 + o] = 0.0f;
    }
    __syncthreads();

    // ======== Mel projection: one thread per (m, h, c) -- 128x2x2 = 512.
    // Plane offsets mod 32 banks: 0/4/8/12 -> conflict-free thread quad.
    // Variable-length loop (wn4[m] = 2..15 float4 iters); packed-FMA dot.
    {
        int m  = tid >> 2;
        int h  = (tid >> 1) & 1;               // frame t0+h
        int c  = tid & 1;                      // channel
        int a0 = wbeg[m];
        int n4 = wn4[m];
        const float4* wt4 = (const float4*)(wtab + (m << 6));
        const float4* q   = (const float4*)(pwb + h*PW_FR + c*PW_OFF + a0);
        vf2 acc = (vf2){0.0f, 0.0f};
        for (int j = 0; j < n4; ++j) {
            float4 w4 = wt4[j];
            float4 rv = q[j];
            acc += (vf2){w4.x, w4.y} * (vf2){rv.x, rv.y};
            acc += (vf2){w4.z, w4.w} * (vf2){rv.z, rv.w};
        }
        size_t base = (((size_t)b * N_MELS + m) * T_FRAMES + t0 + h) * CH + c;
        out[base] = acc.x + acc.y;
    }
}

extern "C" void kernel_launch(void* const* d_in, const int* in_sizes, int n_in,
                              void* d_out, int out_size, void* d_ws, size_t ws_size,
                              hipStream_t stream) {
    const float* x  = (const float*)d_in[0];
    const float* fb = (const float*)d_in[1];
    float* out = (float*)d_out;
    float* ws  = (float*)d_ws;

    setup_kernel<<<40, 256, 0, stream>>>(fb, ws);
    mel_spec_kernel<<<BATCH * (T_FRAMES/2), 512, 0, stream>>>(x, fb, ws, out);
}

// Round 8
// 118.513 us; speedup vs baseline: 2.2953x; 1.1595x over previous
//
#include <hip/hip_runtime.h>
#include <math.h>

#define N_MELS   128
#define N_FFT    2048
#define HOP      512
#define BATCH    8
#define S_LEN    661500
#define CH       2
#define T_FRAMES 1292            // 1 + S_LEN/HOP
#define NBINS    1025            // 1 + N_FFT/2

#define ANG 0.003067961575771282f   // 2*pi/2048

// d_ws layout (byte offsets)
#define WS_WIN     0        // float[2048]   hann window
#define WS_TW      8192     // float2[2048]  W_2048^j
#define WS_WBEG    24576    // int[128]      4-aligned start bin per mel
#define WS_WN4     25088    // int[128]      float4 iteration count per mel
#define WS_WTAB    25600    // float[128*64] dense zero-padded mel weights

// pw planes: [h*PW_FR + c*PW_OFF + f]. PW_FR ≡ 8, PW_OFF ≡ 4 (mod 32 banks)
// so the (m,h) lane pairs in the mel loop hit disjoint bank groups.
#define PW_OFF   1060       // channel-plane stride (floats)
#define PW_FR    2120       // frame-plane stride (floats)

// Full padded buffer: element e in [0,2048) lives at Z2[e + 2*(e>>4)].
#define ZN 2304             // float2 count = 2048 + 2*128 -> 18432 B

// Session ledger (structural space around this shape is EXHAUSTED):
//   R2: 4 frames/256thr, 36.9KB LDS  -> occupancy collapse (-28%)
//   R6: 4 frames/512thr, deferred state -> VGPR spill, 650MB scratch (-360%)
//   R7: 1 frame/thread half-block     -> ILP loss, VALUBusy 57->44 (-54%)
// This 256-thr / 2-frames-per-thread / single-18.4KB-buffer shape keeps
// registers (<=64), LDS (8 blocks/CU), dual-stream ILP, and 4-wave barriers
// simultaneously at their sweet spots. Verified best: 44.1 us dispatch.
typedef float vf2 __attribute__((ext_vector_type(2)));

__device__ __forceinline__ vf2 cnegi(vf2 z){ return (vf2){ z.y, -z.x }; } // -i*z
__device__ __forceinline__ vf2 cmul(vf2 a, vf2 b){
    vf2 t = a.yy * b.yx;                 // v_pk_mul
    vf2 s = (vf2){ -t.x, t.y };          // neg_lo, folds into the fma
    return a.xx * b + s;                 // v_pk_fma
}

// radix-8 DIF butterfly: b[k] = sum_j a[j] * W8^{jk}, W8 = exp(-i*pi/4)
__device__ __forceinline__ void bfly8(const vf2* a, vf2* b) {
    const float C = 0.70710678118654752f;
    vf2 e0=a[0]+a[4], e1=a[1]+a[5], e2=a[2]+a[6], e3=a[3]+a[7];
    vf2 o0=a[0]-a[4], o1=a[1]-a[5], o2=a[2]-a[6], o3=a[3]-a[7];
    vf2 t1 = (o1 + cnegi(o1)) * C;       // o1*W8^1
    vf2 t2 = cnegi(o2);                  // o2*W8^2
    vf2 t3 = (cnegi(o3) - o3) * C;       // o3*W8^3
    {
        vf2 s0=e0+e2, d0=e0-e2;
        vf2 s1=e1+e3, d1=e1-e3;
        b[0]=s0+s1; b[4]=s0-s1;
        vf2 nd1=cnegi(d1);
        b[2]=d0+nd1; b[6]=d0-nd1;
    }
    {
        vf2 s0=o0+t2, d0=o0-t2;
        vf2 s1=t1+t3, d1=t1-t3;
        b[1]=s0+s1; b[5]=s0-s1;
        vf2 nd1=cnegi(d1);
        b[3]=d0+nd1; b[7]=d0-nd1;
    }
}

// Both frames: bfly8 + shared twiddle product tree (depth 3). In-register
// VALU twiddles (R7 lesson: table gathers put VMEM latency on the critical
// path; the tree is shared across both frame streams).
__device__ __forceinline__ void stage_pair(vf2* rA, vf2* rB, vf2 w1) {
    vf2 bqA[8], bqB[8];
    bfly8(rA, bqA);
    bfly8(rB, bqB);
    vf2 w2 = cmul(w1, w1);
    vf2 w3 = cmul(w2, w1);
    vf2 w4 = cmul(w2, w2);
    vf2 w5 = cmul(w4, w1);
    vf2 w6 = cmul(w4, w2);
    vf2 w7 = cmul(w4, w3);
    rA[0] = bqA[0];           rB[0] = bqB[0];
    rA[1] = cmul(w1, bqA[1]); rB[1] = cmul(w1, bqB[1]);
    rA[2] = cmul(w2, bqA[2]); rB[2] = cmul(w2, bqB[2]);
    rA[3] = cmul(w3, bqA[3]); rB[3] = cmul(w3, bqB[3]);
    rA[4] = cmul(w4, bqA[4]); rB[4] = cmul(w4, bqB[4]);
    rA[5] = cmul(w5, bqA[5]); rB[5] = cmul(w5, bqB[5]);
    rA[6] = cmul(w6, bqA[6]); rB[6] = cmul(w6, bqB[6]);
    rA[7] = cmul(w7, bqA[7]); rB[7] = cmul(w7, bqB[7]);
}

// stage-4 radix-4 (s=512, twiddle-free) butterfly
__device__ __forceinline__ void bf4(const vf2* I, vf2* O) {
    vf2 apc=I[0]+I[2], amc=I[0]-I[2];
    vf2 bpd=I[1]+I[3], bmd=I[1]-I[3];
    vf2 nb = cnegi(bmd);
    O[0]=apc+bpd; O[1]=amc+nb;
    O[2]=apc-bpd; O[3]=amc-nb;
}

// two-channel untangle: (|A|^2, |B|^2) for Zf, Zm = Z[N-f]
__device__ __forceinline__ vf2 upair(vf2 Zf, vf2 Zm) {
    vf2 B = (vf2){ Zm.x, -Zm.y };        // conj
    vf2 e = Zf + B;
    vf2 d = Zf - B;
    vf2 ee = e * e;
    vf2 dd = d * d;
    return (vf2){ 0.25f*(ee.x + ee.y), 0.25f*(dd.x + dd.y) };
}

// --- setup: blocks 0..7 build tables; blocks 8..135: mel weight rows ---
__global__ __launch_bounds__(256) void setup_kernel(
        const float* __restrict__ fb, float* __restrict__ ws) {
    int blk = blockIdx.x;
    if (blk < 8) {
        int i = blk * 256 + threadIdx.x;
        float*  win = ws;
        float2* tw  = (float2*)((char*)ws + WS_TW);
        win[i] = 0.5f - 0.5f * cosf(ANG * (float)i);
        float sn, cs; sincosf(-ANG * (float)i, &sn, &cs);
        tw[i] = make_float2(cs, sn);
    } else {
        int m = blk - 8;
        int lane = threadIdx.x;
        if (lane < 64) {
            int*   wbeg = (int*)((char*)ws + WS_WBEG);
            int*   wn4  = (int*)((char*)ws + WS_WN4);
            float* wtab = (float*)((char*)ws + WS_WTAB);
            const float* row = fb + m * NBINS;
            int s = NBINS;      // first nonzero bin
            int e = 0;          // last nonzero bin
            for (int f = lane; f < NBINS; f += 64) {
                if (row[f] != 0.0f) { if (f < s) s = f; if (f > e) e = f; }
            }
            #pragma unroll
            for (int o = 32; o; o >>= 1) {
                s = min(s, __shfl_xor(s, o));
                e = max(e, __shfl_xor(e, o));
            }
            int a0 = s & ~3;              // 4-aligned start; slaney span<=54+3<64
            if (a0 > NBINS - 1) a0 = (NBINS - 1) & ~3;
            int n4 = (e - a0 + 4) >> 2;   // ceil((e-a0+1)/4)
            if (n4 < 1) n4 = 1;
            if (n4 > 16) n4 = 16;
            if (lane == 0) { wbeg[m] = a0; wn4[m] = n4; }
            int f = a0 + lane;
            wtab[(m << 6) + lane] = (f < NBINS) ? row[f] : 0.0f;
        }
    }
}

// --- main: 2 frames per block; full-buffer exchange, frames alternate ---
// 18432 B LDS -> 8 blocks/CU (R2 lesson: bigger LDS collapses occupancy).
__global__ __launch_bounds__(256, 8) void mel_spec_kernel(
        const float* __restrict__ x, const float* __restrict__ fb,
        const float* __restrict__ ws, float* __restrict__ out) {
    __shared__ float4 Zq[ZN/2];          // 18432 B, one full padded buffer
    vf2*   Z2  = (vf2*)Zq;
    float* pwb = (float*)Zq;             // pw planes: [h*2120 + c*1060 + f]

    const float* win  = ws;
    const vf2*   tw   = (const vf2*)((const char*)ws + WS_TW);
    const int*   wbeg = (const int*)((const char*)ws + WS_WBEG);
    const int*   wn4  = (const int*)((const char*)ws + WS_WN4);
    const float* wtab = (const float*)((const char*)ws + WS_WTAB);

    const int tid = threadIdx.x;
    const int bid = blockIdx.x;
    const int b   = bid & 7;              // XCD-contiguous: one batch item per XCD
    const int t0  = (bid >> 3) * 2;       // frames t0, t0+1

    const vf2* xb = (const vf2*)x + (size_t)b * S_LEN;
    const int tbA = t0*HOP - (N_FFT/2);
    const int tbB = tbA + HOP;

    vf2 rA[8], rB[8];
    const int rb = tid + 2*(tid>>4);      // OFFE(tid); +288 per 256 elements

    // ---- Input: frames overlap by 1536 samples (HOP=512=2*256), so
    // frame-B element (tid,k) == frame-A element (tid,k+2). Fast path loads
    // 10 vf2/thread instead of 16.
    if (tbA >= 0 && tbB + (N_FFT - 1) < S_LEN) {
        vf2 v[10];
        #pragma unroll
        for (int k = 0; k < 10; ++k) v[k] = xb[tbA + tid + 256*k];
        #pragma unroll
        for (int k = 0; k < 8; ++k) {
            float w = win[tid + 256*k];
            rA[k] = v[k]   * w;           // v_pk_mul (scalar broadcast)
            rB[k] = v[k+2] * w;
        }
    } else {
        #pragma unroll
        for (int k = 0; k < 8; ++k) {
            int n  = tid + 256*k;
            float w = win[n];
            int sA = tbA + n;
            if (sA < 0) sA = -sA; else if (sA >= S_LEN) sA = 2*S_LEN - 2 - sA;
            rA[k] = xb[sA] * w;
            int sB = tbB + n;
            if (sB < 0) sB = -sB; else if (sB >= S_LEN) sB = 2*S_LEN - 2 - sB;
            rB[k] = xb[sB] * w;
        }
    }

    // ======== Stage 1: radix-8, s=1. Outputs e = 8*tid + k (b128 writes).
    stage_pair(rA, rB, tw[tid]);
    {
        const int f4 = 4*tid + (tid>>1);          // float4 index of OFFE(8*tid)/2
        #pragma unroll
        for (int j = 0; j < 4; ++j)
            Zq[f4+j] = make_float4(rA[2*j].x, rA[2*j].y, rA[2*j+1].x, rA[2*j+1].y);
        __syncthreads();
        #pragma unroll
        for (int k = 0; k < 8; ++k) rA[k] = Z2[rb + 288*k];
        __syncthreads();
        #pragma unroll
        for (int j = 0; j < 4; ++j)
            Zq[f4+j] = make_float4(rB[2*j].x, rB[2*j].y, rB[2*j+1].x, rB[2*j+1].y);
        __syncthreads();
        #pragma unroll
        for (int k = 0; k < 8; ++k) rB[k] = Z2[rb + 288*k];
        __syncthreads();
    }

    // ======== Stage 2: radix-8, s=8. Outputs e = q + 64a + 8k.
    stage_pair(rA, rB, tw[tid & ~7]);
    {
        const int base = (tid & 7) + 72*(tid >> 3);
        #pragma unroll
        for (int k = 0; k < 8; ++k) Z2[base + 8*k + 2*(k>>1)] = rA[k];
        __syncthreads();
        #pragma unroll
        for (int k = 0; k < 8; ++k) rA[k] = Z2[rb + 288*k];
        __syncthreads();
        #pragma unroll
        for (int k = 0; k < 8; ++k) Z2[base + 8*k + 2*(k>>1)] = rB[k];
        __syncthreads();
        #pragma unroll
        for (int k = 0; k < 8; ++k) rB[k] = Z2[rb + 288*k];
        __syncthreads();
    }

    // ======== Stage 3: radix-8, s=64. Outputs e = q + 512a + 64k.
    stage_pair(rA, rB, tw[tid & ~63]);
    // Stage-4 butterfly pair: b1 = tid, b2 = 512-tid (tid=0 -> {0,256}).
    const int b2  = (tid == 0) ? 256 : 512 - tid;
    const int rb2 = b2 + 2*(b2>>4);
    vf2 A1[4], A2[4], B1[4], B2[4];
    {
        const int q = tid & 63;
        const int base = q + 2*(q>>4) + 576*(tid >> 6);
        #pragma unroll
        for (int k = 0; k < 8; ++k) Z2[base + 72*k] = rA[k];
        __syncthreads();
        #pragma unroll
        for (int k = 0; k < 4; ++k) { A1[k] = Z2[rb + 576*k]; A2[k] = Z2[rb2 + 576*k]; }
        __syncthreads();
        #pragma unroll
        for (int k = 0; k < 8; ++k) Z2[base + 72*k] = rB[k];
        __syncthreads();
        #pragma unroll
        for (int k = 0; k < 4; ++k) { B1[k] = Z2[rb + 576*k]; B2[k] = Z2[rb2 + 576*k]; }
        __syncthreads();
    }

    // ======== Stage 4 + untangle, straight-line per frame (registers only,
    // then pw-plane writes into Zq; all Zq reads fenced above).
    // Also zero the 35-float gap [1025,1060) after each plane so the mel
    // loop's tail reads (up to bin 1027 with the short loop) hit exact zeros.
    if (tid < 140) {
        int p = tid / 35;
        int o = tid - p * 35;
        pwb[(p>>1)*PW_FR + (p&1)*PW_OFF + 1025 + o] = 0.0f;
    }
    {
        vf2 O1[4], O2[4];
        bf4(A1, O1); bf4(A2, O2);
        float* pwf = pwb;                          // frame A planes (h=0)
        if (tid == 0) {
            vf2 p;
            p = upair(O1[0], O1[0]); pwf[0]    = p.x; pwf[PW_OFF+0]    = p.y;
            p = upair(O1[1], O1[3]); pwf[512]  = p.x; pwf[PW_OFF+512]  = p.y;
            p = upair(O1[2], O1[2]); pwf[1024] = p.x; pwf[PW_OFF+1024] = p.y;
            p = upair(O2[0], O2[3]); pwf[256]  = p.x; pwf[PW_OFF+256]  = p.y;
            p = upair(O2[1], O2[2]); pwf[768]  = p.x; pwf[PW_OFF+768]  = p.y;
        } else {
            vf2 p;
            p = upair(O1[0], O2[3]); pwf[tid]      = p.x; pwf[PW_OFF+tid]      = p.y;
            p = upair(O1[1], O2[2]); pwf[tid+512]  = p.x; pwf[PW_OFF+tid+512]  = p.y;
            p = upair(O2[0], O1[3]); pwf[512-tid]  = p.x; pwf[PW_OFF+512-tid]  = p.y;
            p = upair(O2[1], O1[2]); pwf[1024-tid] = p.x; pwf[PW_OFF+1024-tid] = p.y;
        }
    }
    {
        vf2 O1[4], O2[4];
        bf4(B1, O1); bf4(B2, O2);
        float* pwf = pwb + PW_FR;                  // frame B planes (h=1)
        if (tid == 0) {
            vf2 p;
            p = upair(O1[0], O1[0]); pwf[0]    = p.x; pwf[PW_OFF+0]    = p.y;
            p = upair(O1[1], O1[3]); pwf[512]  = p.x; pwf[PW_OFF+512]  = p.y;
            p = upair(O1[2], O1[2]); pwf[1024] = p.x; pwf[PW_OFF+1024] = p.y;
            p = upair(O2[0], O2[3]); pwf[256]  = p.x; pwf[PW_OFF+256]  = p.y;
            p = upair(O2[1], O2[2]); pwf[768]  = p.x; pwf[PW_OFF+768]  = p.y;
        } else {
            vf2 p;
            p = upair(O1[0], O2[3]); pwf[tid]      = p.x; pwf[PW_OFF+tid]      = p.y;
            p = upair(O1[1], O2[2]); pwf[tid+512]  = p.x; pwf[PW_OFF+tid+512]  = p.y;
            p = upair(O2[0], O1[3]); pwf[512-tid]  = p.x; pwf[PW_OFF+512-tid]  = p.y;
            p = upair(O2[1], O1[2]); pwf[1024-tid] = p.x; pwf[PW_OFF+1024-tid] = p.y;
        }
    }
    __syncthreads();

    // ======== Mel projection: thread = (m, frame h); both channels -> float2.
    // Variable-length loop (wn4[m] = 2..15 float4 iters); packed-FMA dot.
    {
        int m  = tid >> 1;
        int h  = tid & 1;                      // frame t0+h
        int a0 = wbeg[m];
        int n4 = wn4[m];
        const float4* wt4 = (const float4*)(wtab + (m << 6));
        const float4* q0  = (const float4*)(pwb + h*PW_FR + a0);           // ch0
        const float4* q1  = (const float4*)(pwb + h*PW_FR + PW_OFF + a0);  // ch1
        vf2 acc0 = (vf2){0.0f, 0.0f};
        vf2 acc1 = (vf2){0.0f, 0.0f};
        for (int j = 0; j < n4; ++j) {
            float4 w4 = wt4[j];
            float4 r0 = q0[j];
            float4 r1 = q1[j];
            vf2 wlo = (vf2){w4.x, w4.y}, whi = (vf2){w4.z, w4.w};
            acc0 += wlo * (vf2){r0.x, r0.y};      // v_pk_fma
            acc0 += whi * (vf2){r0.z, r0.w};
            acc1 += wlo * (vf2){r1.x, r1.y};
            acc1 += whi * (vf2){r1.z, r1.w};
        }
        size_t base = (((size_t)b * N_MELS + m) * T_FRAMES + t0 + h) * CH;
        *(float2*)(out + base) = make_float2(acc0.x + acc0.y, acc1.x + acc1.y);
    }
}

extern "C" void kernel_launch(void* const* d_in, const int* in_sizes, int n_in,
                              void* d_out, int out_size, void* d_ws, size_t ws_size,
                              hipStream_t stream) {
    const float* x  = (const float*)d_in[0];
    const float* fb = (const float*)d_in[1];
    float* out = (float*)d_out;
    float* ws  = (float*)d_ws;

    setup_kernel<<<8 + N_MELS, 256, 0, stream>>>(fb, ws);
    mel_spec_kernel<<<BATCH * (T_FRAMES/2), 256, 0, stream>>>(x, fb, ws, out);
}